// Round 1
// baseline (307.150 us; speedup 1.0000x reference)
//
#include <hip/hip_runtime.h>
#include <stdint.h>
#include <math.h>

// RpnLoss: BATCH=4096 samples, A = 5*17*17 = 1445 anchors.
// One block per sample, 256 threads. Reproduces JAX threefry-partitionable PRNG
// (default since JAX 0.4.30): split -> threefry((0,42),(0,i)); 32-bit draws -> o0^o1.
// If loss_reg/acc match but loss_cls fails, flip to legacy (odd-padded) scheme.

#define A_TOT 1445
#define BLOCK 256

__device__ __forceinline__ uint32_t rotl32(uint32_t v, int r){ return (v << r) | (v >> (32 - r)); }

__device__ __forceinline__ void tf2x32(uint32_t k0, uint32_t k1, uint32_t x0, uint32_t x1,
                                       uint32_t& o0, uint32_t& o1)
{
  const uint32_t k2 = k0 ^ k1 ^ 0x1BD11BDAu;
  x0 += k0; x1 += k1;
#define TFR(r) { x0 += x1; x1 = rotl32(x1, (r)); x1 ^= x0; }
  TFR(13) TFR(15) TFR(26) TFR(6)
  x0 += k1; x1 += k2 + 1u;
  TFR(17) TFR(29) TFR(16) TFR(24)
  x0 += k2; x1 += k0 + 2u;
  TFR(13) TFR(15) TFR(26) TFR(6)
  x0 += k0; x1 += k1 + 3u;
  TFR(17) TFR(29) TFR(16) TFR(24)
  x0 += k1; x1 += k2 + 4u;
  TFR(13) TFR(15) TFR(26) TFR(6)
  x0 += k2; x1 += k0 + 5u;
#undef TFR
  o0 = x0; o1 = x1;
}

// logaddexp(0, x)
__device__ __forceinline__ float lae0(float x){
  return fmaxf(x, 0.0f) + log1pf(expf(-fabsf(x)));
}

// Build 256-bin histogram over top-8 bits of r for mask==target, inclusive scan in place.
// Returns total count (== S[255]).
__device__ int hist_total(const uint32_t* __restrict__ r, const int8_t* __restrict__ mask,
                          int8_t target, unsigned int* s_hist, int tid)
{
  s_hist[tid] = 0u;
  __syncthreads();
  for (int j = tid; j < A_TOT; j += BLOCK)
    if (mask[j] == target) atomicAdd(&s_hist[r[j] >> 15], 1u);
  __syncthreads();
  for (int off = 1; off < 256; off <<= 1){
    unsigned int v = (tid >= off) ? s_hist[tid - off] : 0u;
    __syncthreads();
    s_hist[tid] += v;
    __syncthreads();
  }
  return (int)s_hist[255];
}

// Sum lae0(sign*cls[j]) over the k elements with smallest (r, j) among mask==target.
// Requires s_hist to hold the inclusive scan from hist_total. Accumulates into acc.
__device__ void select_sum(const uint32_t* __restrict__ r, const int8_t* __restrict__ mask,
                           const float* __restrict__ s_cls, int8_t target, int k, float sign,
                           unsigned int* s_hist, unsigned int* s_cand, unsigned int* s_scal,
                           int tid, float& acc)
{
  if (k <= 0) return;  // k is block-uniform
  if (tid == 0) s_scal[0] = 0u;  // candidate counter
  // boundary bin B: first bin with S[B] >= k (unique thread writes)
  if ((int)s_hist[tid] >= k && (tid == 0 || (int)s_hist[tid - 1] < k)){
    s_scal[1] = (unsigned int)tid;
    s_scal[2] = (tid == 0) ? 0u : s_hist[tid - 1];  // count before bin B
  }
  __syncthreads();
  const int B = (int)s_scal[1];
  const int m = k - (int)s_scal[2];  // how many to take from bin B (>=1)
  for (int j = tid; j < A_TOT; j += BLOCK){
    if (mask[j] == target){
      uint32_t rv = r[j];
      int bin = (int)(rv >> 15);
      if (bin < B) acc += lae0(sign * s_cls[j]);
      else if (bin == B){
        unsigned int id = atomicAdd(&s_scal[0], 1u);
        // pack (low 15 bits of r, index) -> 26-bit key; uint32 compare == lex order
        s_cand[id] = ((rv & 0x7FFFu) << 11) | (unsigned int)j;
      }
    }
  }
  __syncthreads();
  const int L = (int)s_scal[0];
  for (int c = tid; c < L; c += BLOCK){
    unsigned int my = s_cand[c];
    int rank = 0;
    for (int l = 0; l < L; l++) rank += (s_cand[l] < my) ? 1 : 0;
    if (rank < m) acc += lae0(sign * s_cls[my & 0x7FFu]);
  }
  __syncthreads();  // protect s_hist/s_cand reuse
}

__global__ void __launch_bounds__(BLOCK) rpn_loss_kernel(
    const float* __restrict__ pred_cls, const float* __restrict__ pred_reg,
    const float* __restrict__ gt_bbox, const float* __restrict__ anchor_center,
    const float* __restrict__ anchor_corner, float* __restrict__ accum,
    int N, float invN)
{
  __shared__ float        s_cls[A_TOT];
  __shared__ uint32_t     s_rp[A_TOT];
  __shared__ uint32_t     s_rn[A_TOT];
  __shared__ int8_t       s_mask[A_TOT];
  __shared__ unsigned int s_hist[256];
  __shared__ unsigned int s_cand[A_TOT];
  __shared__ unsigned int s_scal[4];
  __shared__ float        s_red[12];

  const int n   = blockIdx.x;
  const int tid = threadIdx.x;

  const float g0 = gt_bbox[4 * n + 0];
  const float g1 = gt_bbox[4 * n + 1];
  const float g2 = gt_bbox[4 * n + 2];
  const float g3 = gt_bbox[4 * n + 3];
  const float area_a = (g2 - g0) * (g3 - g1);

  // keys: foldlike split of key(42) over 2N; kpos[n]=key_n, kneg[n]=key_{N+n}
  uint32_t kp0, kp1, kn0, kn1;
  tf2x32(0u, 42u, 0u, (uint32_t)n,       kp0, kp1);
  tf2x32(0u, 42u, 0u, (uint32_t)(N + n), kn0, kn1);

  // Phase A: IoU mask + cls + accuracy count + PRNG draws
  float accc = 0.0f;
  const float* cls_base = pred_cls + (size_t)n * A_TOT;
  const float4* cornv = (const float4*)anchor_corner;
  for (int j = tid; j < A_TOT; j += BLOCK){
    float4 cr = cornv[j];
    float ltx = fmaxf(g0, cr.x), lty = fmaxf(g1, cr.y);
    float rbx = fminf(g2, cr.z), rby = fminf(g3, cr.w);
    float wx = fmaxf(rbx - ltx, 0.0f), wy = fmaxf(rby - lty, 0.0f);
    float inter = wx * wy;
    float area_b = (cr.z - cr.x) * (cr.w - cr.y);
    float iou = inter / (area_a + area_b - inter);
    int8_t m = (iou > 0.6f) ? (int8_t)1 : ((iou < 0.3f) ? (int8_t)0 : (int8_t)-1);
    s_mask[j] = m;
    float c = cls_base[j];
    s_cls[j] = c;
    accc += ((c >= 0.6f) == (m == 1)) ? 1.0f : 0.0f;
    uint32_t o0, o1;
    tf2x32(kp0, kp1, 0u, (uint32_t)j, o0, o1);
    s_rp[j] = (o0 ^ o1) >> 9;            // 23-bit r, monotone in u
    tf2x32(kn0, kn1, 0u, (uint32_t)j, o0, o1);
    s_rn[j] = (o0 ^ o1) >> 9;
  }
  __syncthreads();

  // Positive selection
  const int n_pos = hist_total(s_rp, s_mask, 1, s_hist, tid);
  const int k_p = min(n_pos, 16);
  float lc_part = 0.0f;
  select_sum(s_rp, s_mask, s_cls, 1, k_p, -1.0f, s_hist, s_cand, s_scal, tid, lc_part);

  // Negative selection
  const int n_neg = hist_total(s_rn, s_mask, 0, s_hist, tid);
  const int k_n = min(n_neg, (n_pos > 0) ? 3 * n_pos : 48);
  select_sum(s_rn, s_mask, s_cls, 0, k_n, 1.0f, s_hist, s_cand, s_scal, tid, lc_part);

  // Reg loss over all positive anchors (gather only what's needed)
  float lr_part = 0.0f;
  if (n_pos > 0){
    const float gcx = (g0 + g2) * 0.5f, gcy = (g1 + g3) * 0.5f;
    const float gw = g2 - g0, gh = g3 - g1;
    const float4* cenv = (const float4*)anchor_center;
    const float* reg_base = pred_reg + (size_t)n * 4 * A_TOT;
    for (int j = tid; j < A_TOT; j += BLOCK){
      if (s_mask[j] == 1){
        float4 ce = cenv[j];                 // cx, cy, w, h
        float t0 = (gcx - ce.x) / ce.z;
        float t1 = (gcy - ce.y) / ce.w;
        float t2 = logf(gw / ce.z);
        float t3 = logf(gh / ce.w);
        float d0 = reg_base[j]             - t0;
        float d1 = reg_base[A_TOT + j]     - t1;
        float d2 = reg_base[2 * A_TOT + j] - t2;
        float d3 = reg_base[3 * A_TOT + j] - t3;
        lr_part += d0 * d0 + d1 * d1 + d2 * d2 + d3 * d3;
      }
    }
  }

  // Block reduce (3 values) and atomic accumulate
  float v0 = lc_part, v1 = lr_part, v2 = accc;
  for (int off = 32; off > 0; off >>= 1){
    v0 += __shfl_down(v0, off, 64);
    v1 += __shfl_down(v1, off, 64);
    v2 += __shfl_down(v2, off, 64);
  }
  const int wave = tid >> 6, lane = tid & 63;
  if (lane == 0){ s_red[wave] = v0; s_red[4 + wave] = v1; s_red[8 + wave] = v2; }
  __syncthreads();
  if (tid == 0){
    float lc = 0.0f, lr = 0.0f, ac = 0.0f;
    for (int w = 0; w < BLOCK / 64; w++){ lc += s_red[w]; lr += s_red[4 + w]; ac += s_red[8 + w]; }
    int denom = k_p + k_n; if (denom < 1) denom = 1;
    lc /= (float)denom;
    lr = (n_pos > 0) ? (lr / (4.0f * (float)n_pos)) : 0.0f;
    ac *= (1.0f / (float)A_TOT);
    atomicAdd(&accum[0], lc * invN);
    atomicAdd(&accum[1], lr * invN);
    atomicAdd(&accum[2], ac * invN);
  }
}

__global__ void init_kernel(float* accum){
  if (threadIdx.x < 3) accum[threadIdx.x] = 0.0f;
}

__global__ void final_kernel(const float* __restrict__ accum, float* __restrict__ out){
  if (threadIdx.x == 0){
    out[0] = accum[0] + accum[1];  // loss_total = cls + reg
    out[1] = accum[0];             // loss_cls
    out[2] = accum[1];             // loss_reg
    out[3] = accum[2];             // acc_cls
  }
}

extern "C" void kernel_launch(void* const* d_in, const int* in_sizes, int n_in,
                              void* d_out, int out_size, void* d_ws, size_t ws_size,
                              hipStream_t stream)
{
  const float* pred_cls = (const float*)d_in[0];
  const float* pred_reg = (const float*)d_in[1];
  const float* gt_bbox  = (const float*)d_in[2];
  const float* a_center = (const float*)d_in[3];
  const float* a_corner = (const float*)d_in[4];
  float* accum = (float*)d_ws;
  float* out   = (float*)d_out;

  const int N = in_sizes[2] / 4;   // 4096
  const float invN = 1.0f / (float)N;

  hipLaunchKernelGGL(init_kernel, dim3(1), dim3(64), 0, stream, accum);
  hipLaunchKernelGGL(rpn_loss_kernel, dim3(N), dim3(BLOCK), 0, stream,
                     pred_cls, pred_reg, gt_bbox, a_center, a_corner, accum, N, invN);
  hipLaunchKernelGGL(final_kernel, dim3(1), dim3(64), 0, stream, accum, out);
}

// Round 2
// 172.827 us; speedup vs baseline: 1.7772x; 1.7772x over previous
//
#include <hip/hip_runtime.h>
#include <stdint.h>
#include <math.h>

// RpnLoss: BATCH=4096 samples, A = 5*17*17 = 1445 anchors. One block/sample.
// PRNG scheme confirmed bit-exact in R1 (threefry-partitionable):
//   split: key_i = threefry((0,42),(0,i));  kpos[n]=key_n, kneg[n]=key_{N+n}
//   draw j: bits = o0^o1 of threefry(key,(0,j)); rank value r = bits>>9 (monotone in u)
// R2: hash pos key only at positive anchors (compacted), fast __expf/__logf lae0,
// single-wave scan (6 barriers total vs ~45), 11KB LDS -> 32 waves/CU, partials
// instead of global atomics.

#define A_TOT 1445
#define BLOCK 256
#define POS_MAX 256
#define CAND_MAX 192

__device__ __forceinline__ void tf2x32(uint32_t k0, uint32_t k1, uint32_t x0, uint32_t x1,
                                       uint32_t& o0, uint32_t& o1)
{
  const uint32_t k2 = k0 ^ k1 ^ 0x1BD11BDAu;
  x0 += k0; x1 += k1;
#define TFR(r) { x0 += x1; x1 = __builtin_rotateleft32(x1, (r)); x1 ^= x0; }
  TFR(13) TFR(15) TFR(26) TFR(6)
  x0 += k1; x1 += k2 + 1u;
  TFR(17) TFR(29) TFR(16) TFR(24)
  x0 += k2; x1 += k0 + 2u;
  TFR(13) TFR(15) TFR(26) TFR(6)
  x0 += k0; x1 += k1 + 3u;
  TFR(17) TFR(29) TFR(16) TFR(24)
  x0 += k1; x1 += k2 + 4u;
  TFR(13) TFR(15) TFR(26) TFR(6)
  x0 += k2; x1 += k0 + 5u;
#undef TFR
  o0 = x0; o1 = x1;
}

// logaddexp(0,x) via HW exp/log. |x|<~10 here, so 1+e^-|x| >= 1+4.5e-5: no
// catastrophic rounding; rel err ~2^-21 << 3e-2 test threshold.
__device__ __forceinline__ float lae0(float x){
  return fmaxf(x, 0.0f) + __logf(1.0f + __expf(-fabsf(x)));
}

__global__ void __launch_bounds__(BLOCK) rpn_loss_kernel(
    const float* __restrict__ pred_cls, const float* __restrict__ pred_reg,
    const float* __restrict__ gt_bbox, const float* __restrict__ anchor_center,
    const float* __restrict__ anchor_corner,
    float* __restrict__ part,   // [3][N] partials: lc, lr, acc
    int N)
{
  __shared__ uint32_t s_rnm[A_TOT];       // (rn<<2) | enc   enc: 2=pos 1=ignore 0=neg
  __shared__ uint32_t s_hist[256];
  __shared__ uint32_t s_pidx[POS_MAX];
  __shared__ uint32_t s_pr[POS_MAX];
  __shared__ float    s_pcls[POS_MAX];
  __shared__ uint32_t s_cand[CAND_MAX];
  __shared__ uint32_t s_scal[4];          // 0=pos ctr, 1=cand ctr, 2=B, 3=before
  __shared__ uint32_t s_key[4];           // kp0 kp1 kn0 kn1
  __shared__ float    s_red[12];

  const int n   = blockIdx.x;
  const int tid = threadIdx.x;

  // init
  s_hist[tid] = 0u;
  if (tid < 4) s_scal[tid] = 0u;
  if (tid == 0){
    uint32_t a, b;
    tf2x32(0u, 42u, 0u, (uint32_t)n,       a, b); s_key[0] = a; s_key[1] = b;
    tf2x32(0u, 42u, 0u, (uint32_t)(N + n), a, b); s_key[2] = a; s_key[3] = b;
  }
  const float g0 = gt_bbox[4 * n + 0];
  const float g1 = gt_bbox[4 * n + 1];
  const float g2 = gt_bbox[4 * n + 2];
  const float g3 = gt_bbox[4 * n + 3];
  const float area_a = (g2 - g0) * (g3 - g1);
  __syncthreads();                                        // B1
  const uint32_t kp0 = s_key[0], kp1 = s_key[1];
  const uint32_t kn0 = s_key[2], kn1 = s_key[3];

  // ---- Phase A: IoU mask + neg-key hash + histogram + pos compaction + accuracy
  float accc = 0.0f;
  const float*  cls_base = pred_cls + (size_t)n * A_TOT;
  const float4* cornv = (const float4*)anchor_corner;
  for (int j = tid; j < A_TOT; j += BLOCK){
    float4 cr = cornv[j];
    float ltx = fmaxf(g0, cr.x), lty = fmaxf(g1, cr.y);
    float rbx = fminf(g2, cr.z), rby = fminf(g3, cr.w);
    float wx = fmaxf(rbx - ltx, 0.0f), wy = fmaxf(rby - lty, 0.0f);
    float inter = wx * wy;
    float area_b = (cr.z - cr.x) * (cr.w - cr.y);
    float iou = inter / (area_a + area_b - inter);
    bool pos = iou > 0.6f;
    bool neg = iou < 0.3f;
    float c = cls_base[j];
    uint32_t o0, o1;
    tf2x32(kn0, kn1, 0u, (uint32_t)j, o0, o1);
    uint32_t rn = (o0 ^ o1) >> 9;                   // 23-bit
    uint32_t enc = pos ? 2u : (neg ? 0u : 1u);
    s_rnm[j] = (rn << 2) | enc;
    if (neg) atomicAdd(&s_hist[rn >> 15], 1u);
    if (pos){
      uint32_t id = atomicAdd(&s_scal[0], 1u);
      if (id < POS_MAX){ s_pidx[id] = j; s_pcls[id] = c; }
    }
    accc += ((c >= 0.6f) == pos) ? 1.0f : 0.0f;
  }
  __syncthreads();                                        // B2

  const int n_pos = min((int)s_scal[0], POS_MAX);
  // ---- Phase B: pos-key hash for positives only
  for (int t = tid; t < n_pos; t += BLOCK){
    uint32_t o0, o1;
    tf2x32(kp0, kp1, 0u, s_pidx[t], o0, o1);
    s_pr[t] = (o0 ^ o1) >> 9;
  }
  // ---- single-wave inclusive scan of 256-bin histogram (wave 0 only)
  if (tid < 64){
    int b = tid * 4;
    uint32_t v0 = s_hist[b], v1 = s_hist[b+1], v2 = s_hist[b+2], v3 = s_hist[b+3];
    uint32_t p0 = v0, p1 = p0 + v1, p2 = p1 + v2, p3 = p2 + v3;
    uint32_t x = p3;
    #pragma unroll
    for (int off = 1; off < 64; off <<= 1){
      uint32_t t = __shfl_up(x, off, 64);
      x += (tid >= off) ? t : 0u;
    }
    uint32_t excl = x - p3;
    s_hist[b] = p0 + excl; s_hist[b+1] = p1 + excl;
    s_hist[b+2] = p2 + excl; s_hist[b+3] = p3 + excl;
  }
  __syncthreads();                                        // B3

  const int n_neg = (int)s_hist[255];
  const int k_p = min(n_pos, 16);
  const int k_n = min(n_neg, (n_pos > 0) ? 3 * n_pos : 48);

  // boundary bin for negatives (unique writer)
  if (k_n > 0 && (int)s_hist[tid] >= k_n && (tid == 0 || (int)s_hist[tid - 1] < k_n)){
    s_scal[2] = (uint32_t)tid;
    s_scal[3] = (tid == 0) ? 0u : s_hist[tid - 1];
  }

  // ---- positives: rank + bce + reg loss (no shared writes -> overlaps to B4)
  float lc = 0.0f, lr = 0.0f;
  {
    const float gcx = (g0 + g2) * 0.5f, gcy = (g1 + g3) * 0.5f;
    const float gw = g2 - g0, gh = g3 - g1;
    const float4* cenv = (const float4*)anchor_center;
    const float* reg_base = pred_reg + (size_t)n * 4 * A_TOT;
    for (int t = tid; t < n_pos; t += BLOCK){
      uint32_t r = s_pr[t], j = s_pidx[t];
      int rank = 0;
      for (int l = 0; l < n_pos; l++){
        uint32_t r2 = s_pr[l], j2 = s_pidx[l];
        rank += (r2 < r || (r2 == r && j2 < j)) ? 1 : 0;
      }
      if (rank < k_p) lc += lae0(-s_pcls[t]);
      float4 ce = cenv[j];                 // cx, cy, w, h
      float t0 = (gcx - ce.x) / ce.z;
      float t1 = (gcy - ce.y) / ce.w;
      float t2 = __logf(gw / ce.z);
      float t3 = __logf(gh / ce.w);
      float d0 = reg_base[j]             - t0;
      float d1 = reg_base[A_TOT + j]     - t1;
      float d2 = reg_base[2 * A_TOT + j] - t2;
      float d3 = reg_base[3 * A_TOT + j] - t3;
      lr += d0 * d0 + d1 * d1 + d2 * d2 + d3 * d3;
    }
  }
  __syncthreads();                                        // B4

  // ---- negatives: classify vs boundary bin, push boundary candidates
  const int Bb = (int)s_scal[2];
  const int m  = k_n - (int)s_scal[3];
  if (k_n > 0){
    for (int j = tid; j < A_TOT; j += BLOCK){
      uint32_t w = s_rnm[j];
      if ((w & 3u) == 0u){
        int bin = (int)(w >> 17);
        if (bin < Bb) lc += lae0(cls_base[j]);
        else if (bin == Bb){
          uint32_t id = atomicAdd(&s_scal[1], 1u);
          if (id < CAND_MAX) s_cand[id] = (((w >> 2) & 0x7FFFu) << 11) | (uint32_t)j;
        }
      }
    }
  }
  __syncthreads();                                        // B5
  const int L = min((int)s_scal[1], CAND_MAX);
  for (int c = tid; c < L; c += BLOCK){
    uint32_t my = s_cand[c];
    int rank = 0;
    for (int l = 0; l < L; l++) rank += (s_cand[l] < my) ? 1 : 0;
    if (rank < m) lc += lae0(cls_base[my & 0x7FFu]);
  }

  // ---- block reduce 3 floats, write partials
  float v0 = lc, v1 = lr, v2 = accc;
  #pragma unroll
  for (int off = 32; off > 0; off >>= 1){
    v0 += __shfl_down(v0, off, 64);
    v1 += __shfl_down(v1, off, 64);
    v2 += __shfl_down(v2, off, 64);
  }
  const int wave = tid >> 6, lane = tid & 63;
  if (lane == 0){ s_red[wave] = v0; s_red[4 + wave] = v1; s_red[8 + wave] = v2; }
  __syncthreads();                                        // B6
  if (tid == 0){
    float slc = s_red[0] + s_red[1] + s_red[2] + s_red[3];
    float slr = s_red[4] + s_red[5] + s_red[6] + s_red[7];
    float sac = s_red[8] + s_red[9] + s_red[10] + s_red[11];
    int denom = k_p + k_n; if (denom < 1) denom = 1;
    part[n]         = slc / (float)denom;
    part[N + n]     = (n_pos > 0) ? (slr / (4.0f * (float)n_pos)) : 0.0f;
    part[2 * N + n] = sac * (1.0f / (float)A_TOT);
  }
}

__global__ void __launch_bounds__(256) reduce_kernel(const float* __restrict__ part,
                                                     float* __restrict__ out, int N)
{
  const int tid = threadIdx.x;
  float lc = 0.0f, lr = 0.0f, ac = 0.0f;
  for (int i = tid; i < N; i += 256){
    lc += part[i];
    lr += part[N + i];
    ac += part[2 * N + i];
  }
  __shared__ float s[12];
  #pragma unroll
  for (int off = 32; off > 0; off >>= 1){
    lc += __shfl_down(lc, off, 64);
    lr += __shfl_down(lr, off, 64);
    ac += __shfl_down(ac, off, 64);
  }
  const int wave = tid >> 6, lane = tid & 63;
  if (lane == 0){ s[wave] = lc; s[4 + wave] = lr; s[8 + wave] = ac; }
  __syncthreads();
  if (tid == 0){
    float LC = s[0] + s[1] + s[2] + s[3];
    float LR = s[4] + s[5] + s[6] + s[7];
    float AC = s[8] + s[9] + s[10] + s[11];
    float inv = 1.0f / (float)N;
    LC *= inv; LR *= inv; AC *= inv;
    out[0] = LC + LR;
    out[1] = LC;
    out[2] = LR;
    out[3] = AC;
  }
}

extern "C" void kernel_launch(void* const* d_in, const int* in_sizes, int n_in,
                              void* d_out, int out_size, void* d_ws, size_t ws_size,
                              hipStream_t stream)
{
  const float* pred_cls = (const float*)d_in[0];
  const float* pred_reg = (const float*)d_in[1];
  const float* gt_bbox  = (const float*)d_in[2];
  const float* a_center = (const float*)d_in[3];
  const float* a_corner = (const float*)d_in[4];
  float* part = (float*)d_ws;            // 3*N floats
  float* out  = (float*)d_out;

  const int N = in_sizes[2] / 4;         // 4096

  hipLaunchKernelGGL(rpn_loss_kernel, dim3(N), dim3(BLOCK), 0, stream,
                     pred_cls, pred_reg, gt_bbox, a_center, a_corner, part, N);
  hipLaunchKernelGGL(reduce_kernel, dim3(1), dim3(256), 0, stream, part, out, N);
}

// Round 3
// 167.211 us; speedup vs baseline: 1.8369x; 1.0336x over previous
//
#include <hip/hip_runtime.h>
#include <stdint.h>
#include <math.h>

// RpnLoss: BATCH=4096 samples, A = 5*17*17 = 1445 anchors.
// R3: ONE WAVE PER SAMPLE (4 waves/block, grid N/4). Zero __syncthreads.
// rn + cls held in registers (23/lane, unrolled); histogram scan + positive
// ranking via wave shuffles; per-wave LDS only for 256-bin histogram,
// compacted positives, and boundary-bin candidates (~2.3 KB/wave).
// PRNG (bit-exact, verified R1/R2): key_i = threefry((0,42),(0,i));
// kpos[n]=key_n, kneg[n]=key_{N+n}; draw j: r = (o0^o1 of threefry(key,(0,j)))>>9.

#define A_TOT 1445
#define NITER 23        // ceil(1445/64)
#define WPB 4           // waves (=samples) per block
#define POS_MAX 64      // geometric bound on n_pos is ~26 (two anchor shapes max)
#define CAND_MAX 128

__device__ __forceinline__ void tf2x32(uint32_t k0, uint32_t k1, uint32_t x0, uint32_t x1,
                                       uint32_t& o0, uint32_t& o1)
{
  const uint32_t k2 = k0 ^ k1 ^ 0x1BD11BDAu;
  x0 += k0; x1 += k1;
#define TFR(r) { x0 += x1; x1 = __builtin_rotateleft32(x1, (r)); x1 ^= x0; }
  TFR(13) TFR(15) TFR(26) TFR(6)
  x0 += k1; x1 += k2 + 1u;
  TFR(17) TFR(29) TFR(16) TFR(24)
  x0 += k2; x1 += k0 + 2u;
  TFR(13) TFR(15) TFR(26) TFR(6)
  x0 += k0; x1 += k1 + 3u;
  TFR(17) TFR(29) TFR(16) TFR(24)
  x0 += k1; x1 += k2 + 4u;
  TFR(13) TFR(15) TFR(26) TFR(6)
  x0 += k2; x1 += k0 + 5u;
#undef TFR
  o0 = x0; o1 = x1;
}

// logaddexp(0,x) via HW exp/log; rel err ~2^-21 << 3e-2 threshold (passed R2).
__device__ __forceinline__ float lae0(float x){
  return fmaxf(x, 0.0f) + __logf(1.0f + __expf(-fabsf(x)));
}

__global__ void __launch_bounds__(WPB * 64, 4) rpn_loss_kernel(
    const float* __restrict__ pred_cls, const float* __restrict__ pred_reg,
    const float* __restrict__ gt_bbox, const float* __restrict__ anchor_center,
    const float* __restrict__ anchor_corner,
    float* __restrict__ part,   // [3][N] partials: lc, lr, acc
    int N)
{
  __shared__ uint32_t s_hist[WPB][256];
  __shared__ uint32_t s_cand[WPB][CAND_MAX];
  __shared__ uint32_t s_pidx[WPB][POS_MAX];
  __shared__ float    s_pcls[WPB][POS_MAX];
  __shared__ uint32_t s_cnt[WPB][2];      // 0=pos counter, 1=cand counter

  const int w    = threadIdx.x >> 6;
  const int lane = threadIdx.x & 63;
  const int n    = blockIdx.x * WPB + w;

  // zero per-wave LDS (wave-synchronous; d_ws/LDS poisoned 0xAA by harness)
  #pragma unroll
  for (int b = 0; b < 4; b++) s_hist[w][lane * 4 + b] = 0u;
  if (lane < 2) s_cnt[w][lane] = 0u;

  const float g0 = gt_bbox[4 * n + 0];
  const float g1 = gt_bbox[4 * n + 1];
  const float g2 = gt_bbox[4 * n + 2];
  const float g3 = gt_bbox[4 * n + 3];
  const float area_a = (g2 - g0) * (g3 - g1);

  uint32_t kp0, kp1, kn0, kn1;
  tf2x32(0u, 42u, 0u, (uint32_t)n,       kp0, kp1);
  tf2x32(0u, 42u, 0u, (uint32_t)(N + n), kn0, kn1);

  const float*  cls_base = pred_cls + (size_t)n * A_TOT;
  const float4* cornv = (const float4*)anchor_corner;

  uint32_t rn[NITER];
  float    cv[NITER];
  uint32_t negbits = 0u;
  float accc = 0.0f;

  // ---- Phase A: IoU + neg-key hash + histogram + pos compaction + accuracy
  #pragma unroll
  for (int t = 0; t < NITER; t++){
    int j = lane + 64 * t;
    bool valid = (j < A_TOT);          // only t==22 partially valid (lane<37)
    int jc = valid ? j : (A_TOT - 1);
    float4 cr = cornv[jc];
    float c = cls_base[jc];
    cv[t] = c;
    float ltx = fmaxf(g0, cr.x), lty = fmaxf(g1, cr.y);
    float rbx = fminf(g2, cr.z), rby = fminf(g3, cr.w);
    float inter = fmaxf(rbx - ltx, 0.0f) * fmaxf(rby - lty, 0.0f);
    float area_b = (cr.z - cr.x) * (cr.w - cr.y);
    float iou = inter / (area_a + area_b - inter);
    bool pos = valid && (iou > 0.6f);
    bool neg = valid && (iou < 0.3f);
    uint32_t o0, o1;
    tf2x32(kn0, kn1, 0u, (uint32_t)j, o0, o1);
    uint32_t r = (o0 ^ o1) >> 9;       // 23-bit rank value
    rn[t] = r;
    if (neg){ negbits |= (1u << t); atomicAdd(&s_hist[w][r >> 15], 1u); }
    if (pos){
      uint32_t id = atomicAdd(&s_cnt[w][0], 1u);
      if (id < POS_MAX){ s_pidx[w][id] = (uint32_t)j; s_pcls[w][id] = c; }
    }
    if (valid) accc += ((c >= 0.6f) == pos) ? 1.0f : 0.0f;
  }
  // same-wave LDS ops are ordered; no barrier needed anywhere below.

  const int n_pos = min((int)s_cnt[w][0], POS_MAX);
  const int k_p = min(n_pos, 16);

  // ---- inclusive scan of 256-bin histogram (4 bins/lane + wave shuffle scan)
  uint32_t S0, S1, S2, S3;
  {
    int b = lane * 4;
    uint32_t v0 = s_hist[w][b], v1 = s_hist[w][b+1], v2 = s_hist[w][b+2], v3 = s_hist[w][b+3];
    S0 = v0; S1 = S0 + v1; S2 = S1 + v2; S3 = S2 + v3;
    uint32_t x = S3;
    #pragma unroll
    for (int off = 1; off < 64; off <<= 1){
      uint32_t tmp = __shfl_up(x, off, 64);
      if (lane >= off) x += tmp;
    }
    uint32_t excl = x - S3;
    S0 += excl; S1 += excl; S2 += excl; S3 += excl;
    s_hist[w][b] = S0; s_hist[w][b+1] = S1; s_hist[w][b+2] = S2; s_hist[w][b+3] = S3;
  }
  const int n_neg = (int)__shfl(S3, 63, 64);
  const int k_n = min(n_neg, (n_pos > 0) ? 3 * n_pos : 48);

  // ---- boundary bin B = first bin with S[B] >= k_n; m = how many from bin B
  int Bb = 256, m = 0;
  if (k_n > 0){
    unsigned long long bal = __ballot(S3 >= (uint32_t)k_n);
    int fl = __ffsll((unsigned long long)bal) - 1;   // exists: lane63 S3=n_neg>=k_n
    uint32_t t0 = __shfl(S0, fl, 64), t1 = __shfl(S1, fl, 64), t2 = __shfl(S2, fl, 64);
    int sub = (t0 >= (uint32_t)k_n) ? 0 : ((t1 >= (uint32_t)k_n) ? 1 : ((t2 >= (uint32_t)k_n) ? 2 : 3));
    Bb = fl * 4 + sub;
    uint32_t before = (Bb == 0) ? 0u : s_hist[w][Bb - 1];
    m = k_n - (int)before;
  }

  // ---- positives: pos-key hash (one per lane), shuffle ranking, bce + reg loss
  float lc = 0.0f, lr = 0.0f;
  if (n_pos > 0){
    uint32_t myr = 0u, myj = 0u; float myc = 0.0f;
    if (lane < n_pos){
      myj = s_pidx[w][lane];
      myc = s_pcls[w][lane];
      uint32_t o0, o1;
      tf2x32(kp0, kp1, 0u, myj, o0, o1);
      myr = (o0 ^ o1) >> 9;
    }
    int rank = 0;
    for (int l = 0; l < n_pos; l++){
      uint32_t r2 = __shfl(myr, l, 64), j2 = __shfl(myj, l, 64);
      if (lane < n_pos && (r2 < myr || (r2 == myr && j2 < myj))) rank++;
    }
    if (lane < n_pos){
      if (rank < k_p) lc += lae0(-myc);
      float gcx = (g0 + g2) * 0.5f, gcy = (g1 + g3) * 0.5f;
      float gw = g2 - g0, gh = g3 - g1;
      float4 ce = ((const float4*)anchor_center)[myj];
      const float* reg_base = pred_reg + (size_t)n * 4 * A_TOT;
      float t0 = (gcx - ce.x) / ce.z;
      float t1 = (gcy - ce.y) / ce.w;
      float t2 = __logf(gw / ce.z);
      float t3 = __logf(gh / ce.w);
      float d0 = reg_base[myj]             - t0;
      float d1 = reg_base[A_TOT + myj]     - t1;
      float d2 = reg_base[2 * A_TOT + myj] - t2;
      float d3 = reg_base[3 * A_TOT + myj] - t3;
      lr = d0 * d0 + d1 * d1 + d2 * d2 + d3 * d3;
    }
  }

  // ---- negatives: classify vs boundary bin from registers, rank boundary bin
  if (k_n > 0){
    #pragma unroll
    for (int t = 0; t < NITER; t++){
      if (negbits & (1u << t)){
        int bin = (int)(rn[t] >> 15);
        if (bin < Bb) lc += lae0(cv[t]);
        else if (bin == Bb){
          uint32_t id = atomicAdd(&s_cnt[w][1], 1u);
          if (id < CAND_MAX)
            s_cand[w][id] = ((rn[t] & 0x7FFFu) << 11) | (uint32_t)(lane + 64 * t);
        }
      }
    }
    const int L = min((int)s_cnt[w][1], CAND_MAX);
    for (int c = lane; c < L; c += 64){
      uint32_t my = s_cand[w][c];
      int rank = 0;
      for (int l = 0; l < L; l++) rank += (s_cand[w][l] < my) ? 1 : 0;  // broadcast reads
      if (rank < m) lc += lae0(cls_base[my & 0x7FFu]);
    }
  }

  // ---- wave reduce 3 floats, lane 0 writes partials
  float v0 = lc, v1 = lr, v2 = accc;
  #pragma unroll
  for (int off = 32; off > 0; off >>= 1){
    v0 += __shfl_down(v0, off, 64);
    v1 += __shfl_down(v1, off, 64);
    v2 += __shfl_down(v2, off, 64);
  }
  if (lane == 0){
    int denom = k_p + k_n; if (denom < 1) denom = 1;
    part[n]         = v0 / (float)denom;
    part[N + n]     = (n_pos > 0) ? (v1 / (4.0f * (float)n_pos)) : 0.0f;
    part[2 * N + n] = v2 * (1.0f / (float)A_TOT);
  }
}

__global__ void __launch_bounds__(256) reduce_kernel(const float* __restrict__ part,
                                                     float* __restrict__ out, int N)
{
  const int tid = threadIdx.x;
  float lc = 0.0f, lr = 0.0f, ac = 0.0f;
  for (int i = tid; i < N; i += 256){
    lc += part[i];
    lr += part[N + i];
    ac += part[2 * N + i];
  }
  __shared__ float s[12];
  #pragma unroll
  for (int off = 32; off > 0; off >>= 1){
    lc += __shfl_down(lc, off, 64);
    lr += __shfl_down(lr, off, 64);
    ac += __shfl_down(ac, off, 64);
  }
  const int wave = tid >> 6, lane = tid & 63;
  if (lane == 0){ s[wave] = lc; s[4 + wave] = lr; s[8 + wave] = ac; }
  __syncthreads();
  if (tid == 0){
    float LC = s[0] + s[1] + s[2] + s[3];
    float LR = s[4] + s[5] + s[6] + s[7];
    float AC = s[8] + s[9] + s[10] + s[11];
    float inv = 1.0f / (float)N;
    LC *= inv; LR *= inv; AC *= inv;
    out[0] = LC + LR;
    out[1] = LC;
    out[2] = LR;
    out[3] = AC;
  }
}

extern "C" void kernel_launch(void* const* d_in, const int* in_sizes, int n_in,
                              void* d_out, int out_size, void* d_ws, size_t ws_size,
                              hipStream_t stream)
{
  const float* pred_cls = (const float*)d_in[0];
  const float* pred_reg = (const float*)d_in[1];
  const float* gt_bbox  = (const float*)d_in[2];
  const float* a_center = (const float*)d_in[3];
  const float* a_corner = (const float*)d_in[4];
  float* part = (float*)d_ws;            // 3*N floats
  float* out  = (float*)d_out;

  const int N = in_sizes[2] / 4;         // 4096

  hipLaunchKernelGGL(rpn_loss_kernel, dim3(N / WPB), dim3(WPB * 64), 0, stream,
                     pred_cls, pred_reg, gt_bbox, a_center, a_corner, part, N);
  hipLaunchKernelGGL(reduce_kernel, dim3(1), dim3(256), 0, stream, part, out, N);
}